// Round 1
// baseline (1565.799 us; speedup 1.0000x reference)
//
#include <hip/hip_runtime.h>
#include <math.h>

#define BB 256
#define NN 128
#define DD 512
#define NEGV (-9e15f)

// ---------------------------------------------------------------- K1: star = masked mean over rows
__global__ __launch_bounds__(256) void k_avepool(const float* __restrict__ h,
                                                 const float* __restrict__ mask,
                                                 float* __restrict__ star) {
    const int b = blockIdx.x;
    const int t = threadIdx.x;
    const float* hb = h + (size_t)b * NN * DD;
    const float* mb = mask + (size_t)b * NN;
    float acc0 = 0.f, acc1 = 0.f, L = 0.f;
    for (int n = 0; n < NN; ++n) {
        float m = mb[n];
        L += m;
        acc0 += m * hb[n * DD + t];
        acc1 += m * hb[n * DD + t + 256];
    }
    star[b * DD + t] = acc0 / L;
    star[b * DD + t + 256] = acc1 / L;
}

// ---------------------------------------------------------------- K2: GAT (scores + select + softmax + PV)
// grid (4 i-tiles, B).  block 256.  i-tile = 32 rows.
__global__ __launch_bounds__(256) void k_gat(const float* __restrict__ h_in,
                                             const int* __restrict__ A,
                                             const float* __restrict__ a0,
                                             const float* __restrict__ a1,
                                             const float* __restrict__ a2,
                                             const float* __restrict__ a3,
                                             float* __restrict__ h_gat) {
    __shared__ float4 aS4[DD];          // a0..a3 interleaved per d   (8 KB)
    __shared__ float4 hS4[NN * 17];     // h chunk [128][64], pitch 17 f4 (34 KB)
    __shared__ float alphaS[32 * 132];  // softmaxed alpha tile        (16.5 KB)
    __shared__ float4 pS4[32 * 16];     // PV j-half partial           (8 KB)

    const int tid = threadIdx.x;
    const int it = blockIdx.x, b = blockIdx.y;
    const float* hb = h_in + (size_t)b * NN * DD;

    for (int i = tid; i < DD; i += 256)
        aS4[i] = make_float4(a0[i], a1[i], a2[i], a3[i]);

    // ---- score phase: thread = 2 rows x 8 j (j at stride 16) ----
    const int ti = tid >> 4, tj = tid & 15;
    const int li0 = ti * 2, li1 = li0 + 1;
    const int r0 = it * 32 + li0, r1 = r0 + 1;

    float acc0[8][4], acc1[8][4];
    #pragma unroll
    for (int jj = 0; jj < 8; ++jj)
        #pragma unroll
        for (int k = 0; k < 4; ++k) { acc0[jj][k] = 0.f; acc1[jj][k] = 0.f; }

    for (int ck = 0; ck < 8; ++ck) {
        const int d0 = ck * 64;
        #pragma unroll
        for (int q = 0; q < 8; ++q) {
            int l = q * 256 + tid;
            int row = l >> 4, c4 = l & 15;
            hS4[row * 17 + c4] = *(const float4*)(hb + row * DD + d0 + c4 * 4);
        }
        __syncthreads();
        #pragma unroll 2
        for (int c4 = 0; c4 < 16; ++c4) {
            const int dbase = d0 + c4 * 4;
            float4 av0 = aS4[dbase], av1 = aS4[dbase + 1], av2 = aS4[dbase + 2], av3 = aS4[dbase + 3];
            float4 hi0 = hS4[r0 * 17 + c4];
            float4 hi1 = hS4[r1 * 17 + c4];
            #pragma unroll
            for (int jj = 0; jj < 8; ++jj) {
                float4 hj = hS4[(tj + 16 * jj) * 17 + c4];
                float p;
                p = hi0.x * hj.x; acc0[jj][0] += p * av0.x; acc0[jj][1] += p * av0.y; acc0[jj][2] += p * av0.z; acc0[jj][3] += p * av0.w;
                p = hi0.y * hj.y; acc0[jj][0] += p * av1.x; acc0[jj][1] += p * av1.y; acc0[jj][2] += p * av1.z; acc0[jj][3] += p * av1.w;
                p = hi0.z * hj.z; acc0[jj][0] += p * av2.x; acc0[jj][1] += p * av2.y; acc0[jj][2] += p * av2.z; acc0[jj][3] += p * av2.w;
                p = hi0.w * hj.w; acc0[jj][0] += p * av3.x; acc0[jj][1] += p * av3.y; acc0[jj][2] += p * av3.z; acc0[jj][3] += p * av3.w;
                p = hi1.x * hj.x; acc1[jj][0] += p * av0.x; acc1[jj][1] += p * av0.y; acc1[jj][2] += p * av0.z; acc1[jj][3] += p * av0.w;
                p = hi1.y * hj.y; acc1[jj][0] += p * av1.x; acc1[jj][1] += p * av1.y; acc1[jj][2] += p * av1.z; acc1[jj][3] += p * av1.w;
                p = hi1.z * hj.z; acc1[jj][0] += p * av2.x; acc1[jj][1] += p * av2.y; acc1[jj][2] += p * av2.z; acc1[jj][3] += p * av2.w;
                p = hi1.w * hj.w; acc1[jj][0] += p * av3.x; acc1[jj][1] += p * av3.y; acc1[jj][2] += p * av3.z; acc1[jj][3] += p * av3.w;
            }
        }
        __syncthreads();
    }

    // ---- select by A (cndmask chain, no runtime indexing) + leaky relu + row softmax ----
    const int* Ab = A + b * NN * NN;
    float s0[8], s1[8];
    #pragma unroll
    for (int jj = 0; jj < 8; ++jj) {
        const int j = tj + jj * 16;
        int Av = Ab[r0 * NN + j];
        float e = (Av == 1) ? acc0[jj][0] : (Av == 2) ? acc0[jj][1] : (Av == 3) ? acc0[jj][2] : acc0[jj][3];
        float lr = (e > 0.f) ? e : 0.2f * e;
        s0[jj] = (Av >= 1 && Av <= 4) ? lr : NEGV;
        Av = Ab[r1 * NN + j];
        e = (Av == 1) ? acc1[jj][0] : (Av == 2) ? acc1[jj][1] : (Av == 3) ? acc1[jj][2] : acc1[jj][3];
        lr = (e > 0.f) ? e : 0.2f * e;
        s1[jj] = (Av >= 1 && Av <= 4) ? lr : NEGV;
    }
    float m0 = s0[0], m1 = s1[0];
    #pragma unroll
    for (int jj = 1; jj < 8; ++jj) { m0 = fmaxf(m0, s0[jj]); m1 = fmaxf(m1, s1[jj]); }
    #pragma unroll
    for (int off = 1; off < 16; off <<= 1) {
        m0 = fmaxf(m0, __shfl_xor(m0, off));
        m1 = fmaxf(m1, __shfl_xor(m1, off));
    }
    float e0[8], e1[8], sum0 = 0.f, sum1 = 0.f;
    #pragma unroll
    for (int jj = 0; jj < 8; ++jj) {
        e0[jj] = expf(s0[jj] - m0); sum0 += e0[jj];
        e1[jj] = expf(s1[jj] - m1); sum1 += e1[jj];
    }
    #pragma unroll
    for (int off = 1; off < 16; off <<= 1) {
        sum0 += __shfl_xor(sum0, off);
        sum1 += __shfl_xor(sum1, off);
    }
    #pragma unroll
    for (int jj = 0; jj < 8; ++jj) {
        const int j = tj + jj * 16;
        alphaS[li0 * 132 + j] = e0[jj] / sum0;
        alphaS[li1 * 132 + j] = e1[jj] / sum1;
    }
    __syncthreads();

    // ---- PV phase: h_gat = alpha @ h.  thread = 4 rows x 4 d, j split in halves ----
    const int jh = tid >> 7, t2 = tid & 127, gi = t2 >> 4, gd = t2 & 15;
    const int gi4 = gi * 4;
    const int jb = jh * 64;
    for (int ck = 0; ck < 8; ++ck) {
        const int d0 = ck * 64;
        #pragma unroll
        for (int q = 0; q < 8; ++q) {
            int l = q * 256 + tid;
            int row = l >> 4, c4 = l & 15;
            hS4[row * 17 + c4] = *(const float4*)(hb + row * DD + d0 + c4 * 4);
        }
        __syncthreads();
        float4 o0 = make_float4(0.f,0.f,0.f,0.f), o1 = o0, o2 = o0, o3 = o0;
        #pragma unroll 4
        for (int j = jb; j < jb + 64; ++j) {
            float4 hv = hS4[j * 17 + gd];
            float al0 = alphaS[(gi4 + 0) * 132 + j];
            float al1 = alphaS[(gi4 + 1) * 132 + j];
            float al2 = alphaS[(gi4 + 2) * 132 + j];
            float al3 = alphaS[(gi4 + 3) * 132 + j];
            o0.x += al0 * hv.x; o0.y += al0 * hv.y; o0.z += al0 * hv.z; o0.w += al0 * hv.w;
            o1.x += al1 * hv.x; o1.y += al1 * hv.y; o1.z += al1 * hv.z; o1.w += al1 * hv.w;
            o2.x += al2 * hv.x; o2.y += al2 * hv.y; o2.z += al2 * hv.z; o2.w += al2 * hv.w;
            o3.x += al3 * hv.x; o3.y += al3 * hv.y; o3.z += al3 * hv.z; o3.w += al3 * hv.w;
        }
        if (jh == 1) {
            pS4[(gi4 + 0) * 16 + gd] = o0;
            pS4[(gi4 + 1) * 16 + gd] = o1;
            pS4[(gi4 + 2) * 16 + gd] = o2;
            pS4[(gi4 + 3) * 16 + gd] = o3;
        }
        __syncthreads();
        if (jh == 0) {
            float4 p;
            p = pS4[(gi4 + 0) * 16 + gd]; o0.x += p.x; o0.y += p.y; o0.z += p.z; o0.w += p.w;
            p = pS4[(gi4 + 1) * 16 + gd]; o1.x += p.x; o1.y += p.y; o1.z += p.z; o1.w += p.w;
            p = pS4[(gi4 + 2) * 16 + gd]; o2.x += p.x; o2.y += p.y; o2.z += p.z; o2.w += p.w;
            p = pS4[(gi4 + 3) * 16 + gd]; o3.x += p.x; o3.y += p.y; o3.z += p.z; o3.w += p.w;
            float* outp = h_gat + ((size_t)b * NN + it * 32 + gi4) * DD + d0 + gd * 4;
            *(float4*)(outp)          = o0;
            *(float4*)(outp + DD)     = o1;
            *(float4*)(outp + 2 * DD) = o2;
            *(float4*)(outp + 3 * DD) = o3;
        }
        __syncthreads();
    }
}

// ---------------------------------------------------------------- K2b: sigmoid gate toward star + noise + embs acc
// grid (8 rowgroups, B). block 256 (4 waves x 4 rows each).
__global__ __launch_bounds__(256) void k_mix(const float* __restrict__ h_gat,
                                             const float* __restrict__ star,
                                             const float* __restrict__ noise_s,
                                             float* __restrict__ h_out,
                                             float* __restrict__ embs,
                                             int first) {
    const int b = blockIdx.y;
    const int tid = threadIdx.x;
    const int wave = tid >> 6, lane = tid & 63;
    const int row0 = blockIdx.x * 16 + wave * 4;
    const float* stp = star + (size_t)b * DD + lane * 8;
    float4 st0 = *(const float4*)(stp);
    float4 st1 = *(const float4*)(stp + 4);
    const float inv3 = 1.0f / 3.0f;

    for (int rr = 0; rr < 4; ++rr) {
        const int row = row0 + rr;
        const size_t base = ((size_t)b * NN + row) * DD + lane * 8;
        float4 hg0 = *(const float4*)(h_gat + base);
        float4 hg1 = *(const float4*)(h_gat + base + 4);
        float4 n0 = *(const float4*)(noise_s + base);
        float4 n1 = *(const float4*)(noise_s + base + 4);
        float dot = hg0.x*st0.x + hg0.y*st0.y + hg0.z*st0.z + hg0.w*st0.w
                  + hg1.x*st1.x + hg1.y*st1.y + hg1.z*st1.z + hg1.w*st1.w;
        float nn = n0.x*n0.x + n0.y*n0.y + n0.z*n0.z + n0.w*n0.w
                 + n1.x*n1.x + n1.y*n1.y + n1.z*n1.z + n1.w*n1.w;
        #pragma unroll
        for (int off = 1; off < 64; off <<= 1) {
            dot += __shfl_xor(dot, off);
            nn  += __shfl_xor(nn, off);
        }
        const float sim = dot / 22.62741699796952f;   // / sqrt(512)
        const float al = 1.0f / (1.0f + expf(-sim));
        const float ns = 0.4f / fmaxf(sqrtf(nn), 1e-12f);

        float hm, sg, hn[8];
        float hgv[8] = {hg0.x,hg0.y,hg0.z,hg0.w,hg1.x,hg1.y,hg1.z,hg1.w};
        float stv[8] = {st0.x,st0.y,st0.z,st0.w,st1.x,st1.y,st1.z,st1.w};
        float nv [8] = {n0.x,n0.y,n0.z,n0.w,n1.x,n1.y,n1.z,n1.w};
        #pragma unroll
        for (int c = 0; c < 8; ++c) {
            hm = (1.0f - al) * hgv[c] + al * stv[c];
            sg = (hm > 0.f) ? 1.f : ((hm < 0.f) ? -1.f : 0.f);
            hn[c] = hm + sg * nv[c] * ns;
        }
        float4 w0 = make_float4(hn[0], hn[1], hn[2], hn[3]);
        float4 w1 = make_float4(hn[4], hn[5], hn[6], hn[7]);
        *(float4*)(h_out + base) = w0;
        *(float4*)(h_out + base + 4) = w1;
        if (first) {
            float4 ea = make_float4(hn[0]*inv3, hn[1]*inv3, hn[2]*inv3, hn[3]*inv3);
            float4 eb = make_float4(hn[4]*inv3, hn[5]*inv3, hn[6]*inv3, hn[7]*inv3);
            *(float4*)(embs + base) = ea;
            *(float4*)(embs + base + 4) = eb;
        } else {
            float4 ea = *(const float4*)(embs + base);
            float4 eb = *(const float4*)(embs + base + 4);
            ea.x += hn[0]*inv3; ea.y += hn[1]*inv3; ea.z += hn[2]*inv3; ea.w += hn[3]*inv3;
            eb.x += hn[4]*inv3; eb.y += hn[5]*inv3; eb.z += hn[6]*inv3; eb.w += hn[7]*inv3;
            *(float4*)(embs + base) = ea;
            *(float4*)(embs + base + 4) = eb;
        }
    }
}

// ---------------------------------------------------------------- K3: attention pooling star update
__global__ __launch_bounds__(256) void k_attpool(const float* __restrict__ h,
                                                 const float* __restrict__ star_in,
                                                 const float* __restrict__ mask,
                                                 float* __restrict__ star_out) {
    __shared__ float starS[DD];
    __shared__ float simS[NN];
    __shared__ float wS[NN];
    __shared__ float sh_M, sh_inv;
    const int b = blockIdx.x;
    const int tid = threadIdx.x;
    starS[tid] = star_in[b * DD + tid];
    starS[tid + 256] = star_in[b * DD + tid + 256];
    __syncthreads();
    const int wave = tid >> 6, lane = tid & 63;
    const float* hb = h + (size_t)b * NN * DD;
    float4 sv0 = *(const float4*)(&starS[lane * 8]);
    float4 sv1 = *(const float4*)(&starS[lane * 8 + 4]);
    for (int q = 0; q < 32; ++q) {
        const int n = wave * 32 + q;
        const float* hr = hb + n * DD + lane * 8;
        float4 h0 = *(const float4*)(hr);
        float4 h1 = *(const float4*)(hr + 4);
        float dot = h0.x*sv0.x + h0.y*sv0.y + h0.z*sv0.z + h0.w*sv0.w
                  + h1.x*sv1.x + h1.y*sv1.y + h1.z*sv1.z + h1.w*sv1.w;
        #pragma unroll
        for (int off = 1; off < 64; off <<= 1) dot += __shfl_xor(dot, off);
        if (lane == 0) simS[n] = dot;
    }
    __syncthreads();
    if (tid < 64) {
        float v = fmaxf(simS[tid], simS[tid + 64]);
        #pragma unroll
        for (int off = 1; off < 64; off <<= 1) v = fmaxf(v, __shfl_xor(v, off));
        if (tid == 0) sh_M = v;
    }
    __syncthreads();
    const float M = sh_M;
    if (tid < NN) wS[tid] = expf(simS[tid] - M) * mask[b * NN + tid];
    __syncthreads();
    if (tid < 64) {
        float v = wS[tid] + wS[tid + 64];
        #pragma unroll
        for (int off = 1; off < 64; off <<= 1) v += __shfl_xor(v, off);
        if (tid == 0) sh_inv = 1.0f / (v + 1e-24f * expf(-M));
    }
    __syncthreads();
    const float inv = sh_inv;
    float acc0 = 0.f, acc1 = 0.f;
    for (int n = 0; n < NN; ++n) {
        const float w = wS[n];
        acc0 += w * hb[n * DD + tid];
        acc1 += w * hb[n * DD + tid + 256];
    }
    star_out[b * DD + tid] = acc0 * inv;
    star_out[b * DD + tid + 256] = acc1 * inv;
}

// ----------------------------------------------------------------
extern "C" void kernel_launch(void* const* d_in, const int* in_sizes, int n_in,
                              void* d_out, int out_size, void* d_ws, size_t ws_size,
                              hipStream_t stream) {
    const int*   A      = (const int*)d_in[0];
    const float* hidden = (const float*)d_in[1];
    const float* mask   = (const float*)d_in[2];
    const float* a0     = (const float*)d_in[3];
    const float* a1     = (const float*)d_in[4];
    const float* a2     = (const float*)d_in[5];
    const float* a3     = (const float*)d_in[6];
    const float* noise  = (const float*)d_in[7];

    float* out_h    = (float*)d_out;
    float* out_star = out_h + (size_t)BB * NN * DD;
    float* out_embs = out_star + (size_t)BB * DD;

    float* ws_h    = (float*)d_ws;
    float* ws_star = ws_h + (size_t)BB * NN * DD;

    k_avepool<<<BB, 256, 0, stream>>>(hidden, mask, ws_star);

    for (int s = 0; s < 3; ++s) {
        const float* hin = (s == 0) ? hidden : ws_h;
        k_gat<<<dim3(4, BB), 256, 0, stream>>>(hin, A, a0, a1, a2, a3, out_h);
        const float* ns = noise + (size_t)s * BB * NN * DD;
        float* hout = (s == 2) ? out_h : ws_h;
        k_mix<<<dim3(8, BB), 256, 0, stream>>>(out_h, ws_star, ns, hout, out_embs, (s == 0) ? 1 : 0);
        float* so = (s == 2) ? out_star : ws_star;
        k_attpool<<<BB, 256, 0, stream>>>(hout, ws_star, mask, so);
    }
}

// Round 4
// 1157.930 us; speedup vs baseline: 1.3522x; 1.3522x over previous
//
#include <hip/hip_runtime.h>
#include <math.h>

#define BB 256
#define NN 128
#define DD 512
#define NEGV (-9e15f)

// ---------------------------------------------------------------- K1: star = masked mean over rows
__global__ __launch_bounds__(256) void k_avepool(const float* __restrict__ h,
                                                 const float* __restrict__ mask,
                                                 float* __restrict__ star) {
    const int b = blockIdx.x;
    const int t = threadIdx.x;
    const float* hb = h + (size_t)b * NN * DD;
    const float* mb = mask + (size_t)b * NN;
    float acc0 = 0.f, acc1 = 0.f, L = 0.f;
    for (int n = 0; n < NN; ++n) {
        float m = mb[n];
        L += m;
        acc0 += m * hb[n * DD + t];
        acc1 += m * hb[n * DD + t + 256];
    }
    star[b * DD + t] = acc0 / L;
    star[b * DD + t + 256] = acc1 / L;
}

// ---------------------------------------------------------------- K2: GAT — bit-identical to R1 numerics
// grid (4 i-tiles, B). block 256. i-tile = 32 rows.
// Changes vs R1 (all value-preserving): a_k via uniform scalar loads (SGPR),
// PV both-halves-per-thread (no pS4), alpha read as float4, LDS 51.7KB -> 3 blocks/CU.
__global__ __launch_bounds__(256, 3) void k_gat(const float* __restrict__ h_in,
                                                const int* __restrict__ A,
                                                const float* __restrict__ a0,
                                                const float* __restrict__ a1,
                                                const float* __restrict__ a2,
                                                const float* __restrict__ a3,
                                                float* __restrict__ h_gat) {
    __shared__ float4 hS4[NN * 17];      // h chunk [128][64], pitch 17 f4 (34 KB)
    __shared__ float alphaS[32 * 132];   // softmaxed alpha tile (16.9 KB)

    const int tid = threadIdx.x;
    const int it = blockIdx.x, b = blockIdx.y;
    const float* __restrict__ hb = h_in + (size_t)b * NN * DD;

    // ---- score phase: thread = 2 rows x 8 j (j at stride 16) — EXACTLY R1 ----
    const int ti = tid >> 4, tj = tid & 15;
    const int li0 = ti * 2, li1 = li0 + 1;
    const int r0 = it * 32 + li0, r1 = r0 + 1;

    float acc0[8][4], acc1[8][4];
    #pragma unroll
    for (int jj = 0; jj < 8; ++jj)
        #pragma unroll
        for (int k = 0; k < 4; ++k) { acc0[jj][k] = 0.f; acc1[jj][k] = 0.f; }

    for (int ck = 0; ck < 8; ++ck) {
        const int d0 = ck * 64;
        #pragma unroll
        for (int q = 0; q < 8; ++q) {
            int l = q * 256 + tid;
            int row = l >> 4, c4 = l & 15;
            hS4[row * 17 + c4] = *(const float4*)(hb + row * DD + d0 + c4 * 4);
        }
        __syncthreads();
        #pragma unroll 2
        for (int c4 = 0; c4 < 16; ++c4) {
            const int dbase = d0 + c4 * 4;
            // uniform scalar loads -> SGPRs (same values as R1's aS4 staging)
            const float av0x = a0[dbase],     av0y = a1[dbase],     av0z = a2[dbase],     av0w = a3[dbase];
            const float av1x = a0[dbase + 1], av1y = a1[dbase + 1], av1z = a2[dbase + 1], av1w = a3[dbase + 1];
            const float av2x = a0[dbase + 2], av2y = a1[dbase + 2], av2z = a2[dbase + 2], av2w = a3[dbase + 2];
            const float av3x = a0[dbase + 3], av3y = a1[dbase + 3], av3z = a2[dbase + 3], av3w = a3[dbase + 3];
            float4 hi0 = hS4[r0 * 17 + c4];
            float4 hi1 = hS4[r1 * 17 + c4];
            #pragma unroll
            for (int jj = 0; jj < 8; ++jj) {
                float4 hj = hS4[(tj + 16 * jj) * 17 + c4];
                float p;
                p = hi0.x * hj.x; acc0[jj][0] += p * av0x; acc0[jj][1] += p * av0y; acc0[jj][2] += p * av0z; acc0[jj][3] += p * av0w;
                p = hi0.y * hj.y; acc0[jj][0] += p * av1x; acc0[jj][1] += p * av1y; acc0[jj][2] += p * av1z; acc0[jj][3] += p * av1w;
                p = hi0.z * hj.z; acc0[jj][0] += p * av2x; acc0[jj][1] += p * av2y; acc0[jj][2] += p * av2z; acc0[jj][3] += p * av2w;
                p = hi0.w * hj.w; acc0[jj][0] += p * av3x; acc0[jj][1] += p * av3y; acc0[jj][2] += p * av3z; acc0[jj][3] += p * av3w;
                p = hi1.x * hj.x; acc1[jj][0] += p * av0x; acc1[jj][1] += p * av0y; acc1[jj][2] += p * av0z; acc1[jj][3] += p * av0w;
                p = hi1.y * hj.y; acc1[jj][0] += p * av1x; acc1[jj][1] += p * av1y; acc1[jj][2] += p * av1z; acc1[jj][3] += p * av1w;
                p = hi1.z * hj.z; acc1[jj][0] += p * av2x; acc1[jj][1] += p * av2y; acc1[jj][2] += p * av2z; acc1[jj][3] += p * av2w;
                p = hi1.w * hj.w; acc1[jj][0] += p * av3x; acc1[jj][1] += p * av3y; acc1[jj][2] += p * av3z; acc1[jj][3] += p * av3w;
            }
        }
        __syncthreads();
    }

    // ---- select by A + leaky relu + row softmax — EXACTLY R1 ----
    const int* Ab = A + b * NN * NN;
    float s0[8], s1[8];
    #pragma unroll
    for (int jj = 0; jj < 8; ++jj) {
        const int j = tj + jj * 16;
        int Av = Ab[r0 * NN + j];
        float e = (Av == 1) ? acc0[jj][0] : (Av == 2) ? acc0[jj][1] : (Av == 3) ? acc0[jj][2] : acc0[jj][3];
        float lr = (e > 0.f) ? e : 0.2f * e;
        s0[jj] = (Av >= 1 && Av <= 4) ? lr : NEGV;
        Av = Ab[r1 * NN + j];
        e = (Av == 1) ? acc1[jj][0] : (Av == 2) ? acc1[jj][1] : (Av == 3) ? acc1[jj][2] : acc1[jj][3];
        lr = (e > 0.f) ? e : 0.2f * e;
        s1[jj] = (Av >= 1 && Av <= 4) ? lr : NEGV;
    }
    float m0 = s0[0], m1 = s1[0];
    #pragma unroll
    for (int jj = 1; jj < 8; ++jj) { m0 = fmaxf(m0, s0[jj]); m1 = fmaxf(m1, s1[jj]); }
    #pragma unroll
    for (int off = 1; off < 16; off <<= 1) {
        m0 = fmaxf(m0, __shfl_xor(m0, off));
        m1 = fmaxf(m1, __shfl_xor(m1, off));
    }
    float e0[8], e1[8], sum0 = 0.f, sum1 = 0.f;
    #pragma unroll
    for (int jj = 0; jj < 8; ++jj) {
        e0[jj] = expf(s0[jj] - m0); sum0 += e0[jj];
        e1[jj] = expf(s1[jj] - m1); sum1 += e1[jj];
    }
    #pragma unroll
    for (int off = 1; off < 16; off <<= 1) {
        sum0 += __shfl_xor(sum0, off);
        sum1 += __shfl_xor(sum1, off);
    }
    #pragma unroll
    for (int jj = 0; jj < 8; ++jj) {
        const int j = tj + jj * 16;
        alphaS[li0 * 132 + j] = e0[jj] / sum0;
        alphaS[li1 * 132 + j] = e1[jj] / sum1;
    }
    __syncthreads();

    // ---- PV phase: h_gat = alpha @ h. thread = 2 rows x 1 f4-col, both j-halves ----
    // chain per (i,d): j=0..63 sequential, then j=64..127 sequential, then low+=high — EXACTLY R1
    const int gd = tid & 15;
    const int gi = tid >> 4;
    const int pl0 = gi * 2, pl1 = pl0 + 1;
    const float* al0p = &alphaS[pl0 * 132];
    const float* al1p = &alphaS[pl1 * 132];
    for (int ck = 0; ck < 8; ++ck) {
        const int d0 = ck * 64;
        #pragma unroll
        for (int q = 0; q < 8; ++q) {
            int l = q * 256 + tid;
            int row = l >> 4, c4 = l & 15;
            hS4[row * 17 + c4] = *(const float4*)(hb + row * DD + d0 + c4 * 4);
        }
        __syncthreads();
        float4 s00 = make_float4(0.f, 0.f, 0.f, 0.f), s10 = s00, s01 = s00, s11 = s00;
        #pragma unroll 4
        for (int jq = 0; jq < 16; ++jq) {
            float4 a0v = *(const float4*)(al0p + jq * 4);
            float4 a1v = *(const float4*)(al1p + jq * 4);
            float4 hv;
            hv = hS4[(jq * 4 + 0) * 17 + gd];
            s00.x += a0v.x * hv.x; s00.y += a0v.x * hv.y; s00.z += a0v.x * hv.z; s00.w += a0v.x * hv.w;
            s10.x += a1v.x * hv.x; s10.y += a1v.x * hv.y; s10.z += a1v.x * hv.z; s10.w += a1v.x * hv.w;
            hv = hS4[(jq * 4 + 1) * 17 + gd];
            s00.x += a0v.y * hv.x; s00.y += a0v.y * hv.y; s00.z += a0v.y * hv.z; s00.w += a0v.y * hv.w;
            s10.x += a1v.y * hv.x; s10.y += a1v.y * hv.y; s10.z += a1v.y * hv.z; s10.w += a1v.y * hv.w;
            hv = hS4[(jq * 4 + 2) * 17 + gd];
            s00.x += a0v.z * hv.x; s00.y += a0v.z * hv.y; s00.z += a0v.z * hv.z; s00.w += a0v.z * hv.w;
            s10.x += a1v.z * hv.x; s10.y += a1v.z * hv.y; s10.z += a1v.z * hv.z; s10.w += a1v.z * hv.w;
            hv = hS4[(jq * 4 + 3) * 17 + gd];
            s00.x += a0v.w * hv.x; s00.y += a0v.w * hv.y; s00.z += a0v.w * hv.z; s00.w += a0v.w * hv.w;
            s10.x += a1v.w * hv.x; s10.y += a1v.w * hv.y; s10.z += a1v.w * hv.z; s10.w += a1v.w * hv.w;
        }
        #pragma unroll 4
        for (int jq = 16; jq < 32; ++jq) {
            float4 a0v = *(const float4*)(al0p + jq * 4);
            float4 a1v = *(const float4*)(al1p + jq * 4);
            float4 hv;
            hv = hS4[(jq * 4 + 0) * 17 + gd];
            s01.x += a0v.x * hv.x; s01.y += a0v.x * hv.y; s01.z += a0v.x * hv.z; s01.w += a0v.x * hv.w;
            s11.x += a1v.x * hv.x; s11.y += a1v.x * hv.y; s11.z += a1v.x * hv.z; s11.w += a1v.x * hv.w;
            hv = hS4[(jq * 4 + 1) * 17 + gd];
            s01.x += a0v.y * hv.x; s01.y += a0v.y * hv.y; s01.z += a0v.y * hv.z; s01.w += a0v.y * hv.w;
            s11.x += a1v.y * hv.x; s11.y += a1v.y * hv.y; s11.z += a1v.y * hv.z; s11.w += a1v.y * hv.w;
            hv = hS4[(jq * 4 + 2) * 17 + gd];
            s01.x += a0v.z * hv.x; s01.y += a0v.z * hv.y; s01.z += a0v.z * hv.z; s01.w += a0v.z * hv.w;
            s11.x += a1v.z * hv.x; s11.y += a1v.z * hv.y; s11.z += a1v.z * hv.z; s11.w += a1v.z * hv.w;
            hv = hS4[(jq * 4 + 3) * 17 + gd];
            s01.x += a0v.w * hv.x; s01.y += a0v.w * hv.y; s01.z += a0v.w * hv.z; s01.w += a0v.w * hv.w;
            s11.x += a1v.w * hv.x; s11.y += a1v.w * hv.y; s11.z += a1v.w * hv.z; s11.w += a1v.w * hv.w;
        }
        s00.x += s01.x; s00.y += s01.y; s00.z += s01.z; s00.w += s01.w;
        s10.x += s11.x; s10.y += s11.y; s10.z += s11.z; s10.w += s11.w;
        float* outp = h_gat + ((size_t)b * NN + it * 32 + pl0) * DD + d0 + gd * 4;
        *(float4*)(outp)      = s00;
        *(float4*)(outp + DD) = s10;
        __syncthreads();
    }
}

// ---------------------------------------------------------------- K2b: sigmoid gate toward star + noise + embs acc
__global__ __launch_bounds__(256) void k_mix(const float* __restrict__ h_gat,
                                             const float* __restrict__ star,
                                             const float* __restrict__ noise_s,
                                             float* __restrict__ h_out,
                                             float* __restrict__ embs,
                                             int first) {
    const int b = blockIdx.y;
    const int tid = threadIdx.x;
    const int wave = tid >> 6, lane = tid & 63;
    const int row0 = blockIdx.x * 16 + wave * 4;
    const float* stp = star + (size_t)b * DD + lane * 8;
    float4 st0 = *(const float4*)(stp);
    float4 st1 = *(const float4*)(stp + 4);
    const float inv3 = 1.0f / 3.0f;

    for (int rr = 0; rr < 4; ++rr) {
        const int row = row0 + rr;
        const size_t base = ((size_t)b * NN + row) * DD + lane * 8;
        float4 hg0 = *(const float4*)(h_gat + base);
        float4 hg1 = *(const float4*)(h_gat + base + 4);
        float4 n0 = *(const float4*)(noise_s + base);
        float4 n1 = *(const float4*)(noise_s + base + 4);
        float dot = hg0.x*st0.x + hg0.y*st0.y + hg0.z*st0.z + hg0.w*st0.w
                  + hg1.x*st1.x + hg1.y*st1.y + hg1.z*st1.z + hg1.w*st1.w;
        float nn = n0.x*n0.x + n0.y*n0.y + n0.z*n0.z + n0.w*n0.w
                 + n1.x*n1.x + n1.y*n1.y + n1.z*n1.z + n1.w*n1.w;
        #pragma unroll
        for (int off = 1; off < 64; off <<= 1) {
            dot += __shfl_xor(dot, off);
            nn  += __shfl_xor(nn, off);
        }
        const float sim = dot / 22.62741699796952f;   // / sqrt(512)
        const float al = 1.0f / (1.0f + expf(-sim));
        const float ns = 0.4f / fmaxf(sqrtf(nn), 1e-12f);

        float hm, sg, hn[8];
        float hgv[8] = {hg0.x,hg0.y,hg0.z,hg0.w,hg1.x,hg1.y,hg1.z,hg1.w};
        float stv[8] = {st0.x,st0.y,st0.z,st0.w,st1.x,st1.y,st1.z,st1.w};
        float nv [8] = {n0.x,n0.y,n0.z,n0.w,n1.x,n1.y,n1.z,n1.w};
        #pragma unroll
        for (int c = 0; c < 8; ++c) {
            hm = (1.0f - al) * hgv[c] + al * stv[c];
            sg = (hm > 0.f) ? 1.f : ((hm < 0.f) ? -1.f : 0.f);
            hn[c] = hm + sg * nv[c] * ns;
        }
        float4 w0 = make_float4(hn[0], hn[1], hn[2], hn[3]);
        float4 w1 = make_float4(hn[4], hn[5], hn[6], hn[7]);
        *(float4*)(h_out + base) = w0;
        *(float4*)(h_out + base + 4) = w1;
        if (first) {
            float4 ea = make_float4(hn[0]*inv3, hn[1]*inv3, hn[2]*inv3, hn[3]*inv3);
            float4 eb = make_float4(hn[4]*inv3, hn[5]*inv3, hn[6]*inv3, hn[7]*inv3);
            *(float4*)(embs + base) = ea;
            *(float4*)(embs + base + 4) = eb;
        } else {
            float4 ea = *(const float4*)(embs + base);
            float4 eb = *(const float4*)(embs + base + 4);
            ea.x += hn[0]*inv3; ea.y += hn[1]*inv3; ea.z += hn[2]*inv3; ea.w += hn[3]*inv3;
            eb.x += hn[4]*inv3; eb.y += hn[5]*inv3; eb.z += hn[6]*inv3; eb.w += hn[7]*inv3;
            *(float4*)(embs + base) = ea;
            *(float4*)(embs + base + 4) = eb;
        }
    }
}

// ---------------------------------------------------------------- K3: attention pooling star update
__global__ __launch_bounds__(256) void k_attpool(const float* __restrict__ h,
                                                 const float* __restrict__ star_in,
                                                 const float* __restrict__ mask,
                                                 float* __restrict__ star_out) {
    __shared__ float starS[DD];
    __shared__ float simS[NN];
    __shared__ float wS[NN];
    __shared__ float sh_M, sh_inv;
    const int b = blockIdx.x;
    const int tid = threadIdx.x;
    starS[tid] = star_in[b * DD + tid];
    starS[tid + 256] = star_in[b * DD + tid + 256];
    __syncthreads();
    const int wave = tid >> 6, lane = tid & 63;
    const float* hb = h + (size_t)b * NN * DD;
    float4 sv0 = *(const float4*)(&starS[lane * 8]);
    float4 sv1 = *(const float4*)(&starS[lane * 8 + 4]);
    for (int q = 0; q < 32; ++q) {
        const int n = wave * 32 + q;
        const float* hr = hb + n * DD + lane * 8;
        float4 h0 = *(const float4*)(hr);
        float4 h1 = *(const float4*)(hr + 4);
        float dot = h0.x*sv0.x + h0.y*sv0.y + h0.z*sv0.z + h0.w*sv0.w
                  + h1.x*sv1.x + h1.y*sv1.y + h1.z*sv1.z + h1.w*sv1.w;
        #pragma unroll
        for (int off = 1; off < 64; off <<= 1) dot += __shfl_xor(dot, off);
        if (lane == 0) simS[n] = dot;
    }
    __syncthreads();
    if (tid < 64) {
        float v = fmaxf(simS[tid], simS[tid + 64]);
        #pragma unroll
        for (int off = 1; off < 64; off <<= 1) v = fmaxf(v, __shfl_xor(v, off));
        if (tid == 0) sh_M = v;
    }
    __syncthreads();
    const float M = sh_M;
    if (tid < NN) wS[tid] = expf(simS[tid] - M) * mask[b * NN + tid];
    __syncthreads();
    if (tid < 64) {
        float v = wS[tid] + wS[tid + 64];
        #pragma unroll
        for (int off = 1; off < 64; off <<= 1) v += __shfl_xor(v, off);
        if (tid == 0) sh_inv = 1.0f / (v + 1e-24f * expf(-M));
    }
    __syncthreads();
    const float inv = sh_inv;
    float acc0 = 0.f, acc1 = 0.f;
    for (int n = 0; n < NN; ++n) {
        const float w = wS[n];
        acc0 += w * hb[n * DD + tid];
        acc1 += w * hb[n * DD + tid + 256];
    }
    star_out[b * DD + tid] = acc0 * inv;
    star_out[b * DD + tid + 256] = acc1 * inv;
}

// ----------------------------------------------------------------
extern "C" void kernel_launch(void* const* d_in, const int* in_sizes, int n_in,
                              void* d_out, int out_size, void* d_ws, size_t ws_size,
                              hipStream_t stream) {
    const int*   A      = (const int*)d_in[0];
    const float* hidden = (const float*)d_in[1];
    const float* mask   = (const float*)d_in[2];
    const float* a0     = (const float*)d_in[3];
    const float* a1     = (const float*)d_in[4];
    const float* a2     = (const float*)d_in[5];
    const float* a3     = (const float*)d_in[6];
    const float* noise  = (const float*)d_in[7];

    float* out_h    = (float*)d_out;
    float* out_star = out_h + (size_t)BB * NN * DD;
    float* out_embs = out_star + (size_t)BB * DD;

    float* ws_h    = (float*)d_ws;
    float* ws_star = ws_h + (size_t)BB * NN * DD;

    k_avepool<<<BB, 256, 0, stream>>>(hidden, mask, ws_star);

    for (int s = 0; s < 3; ++s) {
        const float* hin = (s == 0) ? hidden : ws_h;
        k_gat<<<dim3(4, BB), 256, 0, stream>>>(hin, A, a0, a1, a2, a3, out_h);
        const float* ns = noise + (size_t)s * BB * NN * DD;
        float* hout = (s == 2) ? out_h : ws_h;
        k_mix<<<dim3(8, BB), 256, 0, stream>>>(out_h, ws_star, ns, hout, out_embs, (s == 0) ? 1 : 0);
        float* so = (s == 2) ? out_star : ws_star;
        k_attpool<<<BB, 256, 0, stream>>>(hout, ws_star, mask, so);
    }
}

// Round 5
// 976.253 us; speedup vs baseline: 1.6039x; 1.1861x over previous
//
#include <hip/hip_runtime.h>
#include <math.h>

#define BB 256
#define NN 128
#define DD 512
#define NEGV (-9e15f)

// ---------------------------------------------------------------- K1: star = masked mean over rows
__global__ __launch_bounds__(256) void k_avepool(const float* __restrict__ h,
                                                 const float* __restrict__ mask,
                                                 float* __restrict__ star) {
    const int b = blockIdx.x;
    const int t = threadIdx.x;
    const float* hb = h + (size_t)b * NN * DD;
    const float* mb = mask + (size_t)b * NN;
    float acc0 = 0.f, acc1 = 0.f, L = 0.f;
    for (int n = 0; n < NN; ++n) {
        float m = mb[n];
        L += m;
        acc0 += m * hb[n * DD + t];
        acc1 += m * hb[n * DD + t + 256];
    }
    star[b * DD + t] = acc0 / L;
    star[b * DD + t + 256] = acc1 / L;
}

// ---------------------------------------------------------------- K2: GAT — symmetric score, bit-identical chains to R1
// one block per batch, 1024 threads (16 waves).
// e_k(i,j)=e_k(j,i) bit-exactly (commutative mul, same d-chain) -> compute upper
// triangle only (544 tiles of 2 rows x 8 cols), write both selections to esel LDS.
// hS4 is XOR-swizzled by (row>>3)&7 to kill the stride-8-row bank conflict.
__global__ __launch_bounds__(1024, 1) void k_gat(const float* __restrict__ h_in,
                                                 const int* __restrict__ A,
                                                 const float* __restrict__ a0,
                                                 const float* __restrict__ a1,
                                                 const float* __restrict__ a2,
                                                 const float* __restrict__ a3,
                                                 float* __restrict__ h_gat) {
    __shared__ float4 hS4[NN * 17];      // h chunk [128][64], swizzled col, 34.8 KB
    __shared__ float  eselS[NN * 132];   // selected scores -> alpha, 67.6 KB
    __shared__ float4 pS4[NN * 16];      // PV j-half partials, 32 KB

    const int tid = threadIdx.x;
    const int b = blockIdx.x;
    const float* __restrict__ hb = h_in + (size_t)b * NN * DD;

    // ---- job assignment: tile (jr, jjb): rows {2jr,2jr+1}, cols {8jjb..8jjb+7}, jjb >= jr>>2 ----
    const bool hasJob = tid < 544;
    int jr = 0, jjb = 0;
    if (hasJob) {
        int rem = tid;
        for (int rr = 0; rr < 64; ++rr) {
            int c = 16 - (rr >> 2);
            if (rem < c) { jr = rr; jjb = (rr >> 2) + rem; break; }
            rem -= c;
        }
    }
    const int i0 = jr * 2, i1 = i0 + 1;
    const int jb8 = jjb * 8;
    const int swi = (jr >> 2) & 7;       // == (i0>>3)&7 == (i1>>3)&7
    const int swj = jjb & 7;             // == (j>>3)&7 for j in band

    auto stage = [&](int d0) {
        #pragma unroll
        for (int q = 0; q < 2; ++q) {
            int l = q * 1024 + tid;
            int row = l >> 4, c4 = l & 15;
            hS4[row * 17 + (c4 ^ ((row >> 3) & 7))] = *(const float4*)(hb + row * DD + d0 + c4 * 4);
        }
    };

    float acc0[8][4], acc1[8][4];
    #pragma unroll
    for (int jj = 0; jj < 8; ++jj)
        #pragma unroll
        for (int k = 0; k < 4; ++k) { acc0[jj][k] = 0.f; acc1[jj][k] = 0.f; }

    // ================= score phase (chains exactly R1 per pair) =================
    for (int ck = 0; ck < 8; ++ck) {
        const int d0 = ck * 64;
        stage(d0);
        __syncthreads();
        if (hasJob) {
            #pragma unroll 2
            for (int c4 = 0; c4 < 16; ++c4) {
                const int dbase = d0 + c4 * 4;
                const float av0x = a0[dbase],     av0y = a1[dbase],     av0z = a2[dbase],     av0w = a3[dbase];
                const float av1x = a0[dbase + 1], av1y = a1[dbase + 1], av1z = a2[dbase + 1], av1w = a3[dbase + 1];
                const float av2x = a0[dbase + 2], av2y = a1[dbase + 2], av2z = a2[dbase + 2], av2w = a3[dbase + 2];
                const float av3x = a0[dbase + 3], av3y = a1[dbase + 3], av3z = a2[dbase + 3], av3w = a3[dbase + 3];
                float4 hi0 = hS4[i0 * 17 + (c4 ^ swi)];
                float4 hi1 = hS4[i1 * 17 + (c4 ^ swi)];
                #pragma unroll
                for (int jj = 0; jj < 8; ++jj) {
                    float4 hj = hS4[(jb8 + jj) * 17 + (c4 ^ swj)];
                    float p;
                    p = hi0.x * hj.x; acc0[jj][0] += p * av0x; acc0[jj][1] += p * av0y; acc0[jj][2] += p * av0z; acc0[jj][3] += p * av0w;
                    p = hi0.y * hj.y; acc0[jj][0] += p * av1x; acc0[jj][1] += p * av1y; acc0[jj][2] += p * av1z; acc0[jj][3] += p * av1w;
                    p = hi0.z * hj.z; acc0[jj][0] += p * av2x; acc0[jj][1] += p * av2y; acc0[jj][2] += p * av2z; acc0[jj][3] += p * av2w;
                    p = hi0.w * hj.w; acc0[jj][0] += p * av3x; acc0[jj][1] += p * av3y; acc0[jj][2] += p * av3z; acc0[jj][3] += p * av3w;
                    p = hi1.x * hj.x; acc1[jj][0] += p * av0x; acc1[jj][1] += p * av0y; acc1[jj][2] += p * av0z; acc1[jj][3] += p * av0w;
                    p = hi1.y * hj.y; acc1[jj][0] += p * av1x; acc1[jj][1] += p * av1y; acc1[jj][2] += p * av1z; acc1[jj][3] += p * av1w;
                    p = hi1.z * hj.z; acc1[jj][0] += p * av2x; acc1[jj][1] += p * av2y; acc1[jj][2] += p * av2z; acc1[jj][3] += p * av2w;
                    p = hi1.w * hj.w; acc1[jj][0] += p * av3x; acc1[jj][1] += p * av3y; acc1[jj][2] += p * av3z; acc1[jj][3] += p * av3w;
                }
            }
        }
        __syncthreads();
    }

    // ================= selection (both triangles) -> esel =================
    {
        auto selv = [](const float* a4, int Av) -> float {
            float e = (Av == 1) ? a4[0] : (Av == 2) ? a4[1] : (Av == 3) ? a4[2] : a4[3];
            float lr = (e > 0.f) ? e : 0.2f * e;
            return (Av >= 1 && Av <= 4) ? lr : NEGV;
        };
        if (hasJob) {
            const int* __restrict__ Ab = A + (size_t)b * NN * NN;
            #pragma unroll
            for (int jj = 0; jj < 8; ++jj) {
                const int j = jb8 + jj;
                int Av;
                Av = Ab[i0 * NN + j];  eselS[i0 * 132 + j] = selv(acc0[jj], Av);
                Av = Ab[i1 * NN + j];  eselS[i1 * 132 + j] = selv(acc1[jj], Av);
                Av = Ab[j * NN + i0];  eselS[j * 132 + i0] = selv(acc0[jj], Av);
                Av = Ab[j * NN + i1];  eselS[j * 132 + i1] = selv(acc1[jj], Av);
            }
        }
        __syncthreads();
    }

    // ================= row softmax — EXACTLY R1's tree and lane mapping =================
    {
        const int it4 = tid >> 8;            // 0..3 (32-row band)
        const int sub = tid & 255;
        const int ti = sub >> 4, tj = sub & 15;
        const int li0 = it4 * 32 + ti * 2, li1 = li0 + 1;
        float s0[8], s1[8];
        #pragma unroll
        for (int jj = 0; jj < 8; ++jj) {
            s0[jj] = eselS[li0 * 132 + tj + 16 * jj];
            s1[jj] = eselS[li1 * 132 + tj + 16 * jj];
        }
        float m0 = s0[0], m1 = s1[0];
        #pragma unroll
        for (int jj = 1; jj < 8; ++jj) { m0 = fmaxf(m0, s0[jj]); m1 = fmaxf(m1, s1[jj]); }
        #pragma unroll
        for (int off = 1; off < 16; off <<= 1) {
            m0 = fmaxf(m0, __shfl_xor(m0, off));
            m1 = fmaxf(m1, __shfl_xor(m1, off));
        }
        float e0[8], e1[8], sum0 = 0.f, sum1 = 0.f;
        #pragma unroll
        for (int jj = 0; jj < 8; ++jj) {
            e0[jj] = expf(s0[jj] - m0); sum0 += e0[jj];
            e1[jj] = expf(s1[jj] - m1); sum1 += e1[jj];
        }
        #pragma unroll
        for (int off = 1; off < 16; off <<= 1) {
            sum0 += __shfl_xor(sum0, off);
            sum1 += __shfl_xor(sum1, off);
        }
        #pragma unroll
        for (int jj = 0; jj < 8; ++jj) {
            eselS[li0 * 132 + tj + 16 * jj] = e0[jj] / sum0;
            eselS[li1 * 132 + tj + 16 * jj] = e1[jj] / sum1;
        }
    }
    __syncthreads();

    // ================= PV phase: 4 rows x 1 f4col x 1 j-half per thread =================
    // chain per (i,d): j-half sequential (R1 order), then low += high via pS4 (R1 order)
    const int jh = tid >> 9, t2 = tid & 511;
    const int gd = t2 & 15, gi = t2 >> 4;          // gi 0..31, rows 4gi..4gi+3
    const int r0p = gi * 4;
    const float* alp0 = &eselS[(r0p + 0) * 132 + jh * 64];
    const float* alp1 = &eselS[(r0p + 1) * 132 + jh * 64];
    const float* alp2 = &eselS[(r0p + 2) * 132 + jh * 64];
    const float* alp3 = &eselS[(r0p + 3) * 132 + jh * 64];
    for (int ck = 0; ck < 8; ++ck) {
        const int d0 = ck * 64;
        stage(d0);
        __syncthreads();
        float4 s0 = make_float4(0.f, 0.f, 0.f, 0.f), s1 = s0, s2 = s0, s3 = s0;
        #pragma unroll 4
        for (int jq = 0; jq < 16; ++jq) {
            float4 a0v = *(const float4*)(alp0 + jq * 4);
            float4 a1v = *(const float4*)(alp1 + jq * 4);
            float4 a2v = *(const float4*)(alp2 + jq * 4);
            float4 a3v = *(const float4*)(alp3 + jq * 4);
            const int jb = jh * 64 + jq * 4;
            float4 hv;
            hv = hS4[(jb + 0) * 17 + (gd ^ (((jq * 4 + 0) >> 3) & 7))];
            s0.x += a0v.x * hv.x; s0.y += a0v.x * hv.y; s0.z += a0v.x * hv.z; s0.w += a0v.x * hv.w;
            s1.x += a1v.x * hv.x; s1.y += a1v.x * hv.y; s1.z += a1v.x * hv.z; s1.w += a1v.x * hv.w;
            s2.x += a2v.x * hv.x; s2.y += a2v.x * hv.y; s2.z += a2v.x * hv.z; s2.w += a2v.x * hv.w;
            s3.x += a3v.x * hv.x; s3.y += a3v.x * hv.y; s3.z += a3v.x * hv.z; s3.w += a3v.x * hv.w;
            hv = hS4[(jb + 1) * 17 + (gd ^ (((jq * 4 + 1) >> 3) & 7))];
            s0.x += a0v.y * hv.x; s0.y += a0v.y * hv.y; s0.z += a0v.y * hv.z; s0.w += a0v.y * hv.w;
            s1.x += a1v.y * hv.x; s1.y += a1v.y * hv.y; s1.z += a1v.y * hv.z; s1.w += a1v.y * hv.w;
            s2.x += a2v.y * hv.x; s2.y += a2v.y * hv.y; s2.z += a2v.y * hv.z; s2.w += a2v.y * hv.w;
            s3.x += a3v.y * hv.x; s3.y += a3v.y * hv.y; s3.z += a3v.y * hv.z; s3.w += a3v.y * hv.w;
            hv = hS4[(jb + 2) * 17 + (gd ^ (((jq * 4 + 2) >> 3) & 7))];
            s0.x += a0v.z * hv.x; s0.y += a0v.z * hv.y; s0.z += a0v.z * hv.z; s0.w += a0v.z * hv.w;
            s1.x += a1v.z * hv.x; s1.y += a1v.z * hv.y; s1.z += a1v.z * hv.z; s1.w += a1v.z * hv.w;
            s2.x += a2v.z * hv.x; s2.y += a2v.z * hv.y; s2.z += a2v.z * hv.z; s2.w += a2v.z * hv.w;
            s3.x += a3v.z * hv.x; s3.y += a3v.z * hv.y; s3.z += a3v.z * hv.z; s3.w += a3v.z * hv.w;
            hv = hS4[(jb + 3) * 17 + (gd ^ (((jq * 4 + 3) >> 3) & 7))];
            s0.x += a0v.w * hv.x; s0.y += a0v.w * hv.y; s0.z += a0v.w * hv.z; s0.w += a0v.w * hv.w;
            s1.x += a1v.w * hv.x; s1.y += a1v.w * hv.y; s1.z += a1v.w * hv.z; s1.w += a1v.w * hv.w;
            s2.x += a2v.w * hv.x; s2.y += a2v.w * hv.y; s2.z += a2v.w * hv.z; s2.w += a2v.w * hv.w;
            s3.x += a3v.w * hv.x; s3.y += a3v.w * hv.y; s3.z += a3v.w * hv.z; s3.w += a3v.w * hv.w;
        }
        if (jh == 1) {
            pS4[(r0p + 0) * 16 + gd] = s0;
            pS4[(r0p + 1) * 16 + gd] = s1;
            pS4[(r0p + 2) * 16 + gd] = s2;
            pS4[(r0p + 3) * 16 + gd] = s3;
        }
        __syncthreads();
        if (jh == 0) {
            float4 p;
            p = pS4[(r0p + 0) * 16 + gd]; s0.x += p.x; s0.y += p.y; s0.z += p.z; s0.w += p.w;
            p = pS4[(r0p + 1) * 16 + gd]; s1.x += p.x; s1.y += p.y; s1.z += p.z; s1.w += p.w;
            p = pS4[(r0p + 2) * 16 + gd]; s2.x += p.x; s2.y += p.y; s2.z += p.z; s2.w += p.w;
            p = pS4[(r0p + 3) * 16 + gd]; s3.x += p.x; s3.y += p.y; s3.z += p.z; s3.w += p.w;
            float* outp = h_gat + ((size_t)b * NN + r0p) * DD + d0 + gd * 4;
            *(float4*)(outp)          = s0;
            *(float4*)(outp + DD)     = s1;
            *(float4*)(outp + 2 * DD) = s2;
            *(float4*)(outp + 3 * DD) = s3;
        }
        __syncthreads();
    }
}

// ---------------------------------------------------------------- K2b: sigmoid gate toward star + noise + embs acc
__global__ __launch_bounds__(256) void k_mix(const float* __restrict__ h_gat,
                                             const float* __restrict__ star,
                                             const float* __restrict__ noise_s,
                                             float* __restrict__ h_out,
                                             float* __restrict__ embs,
                                             int first) {
    const int b = blockIdx.y;
    const int tid = threadIdx.x;
    const int wave = tid >> 6, lane = tid & 63;
    const int row0 = blockIdx.x * 16 + wave * 4;
    const float* stp = star + (size_t)b * DD + lane * 8;
    float4 st0 = *(const float4*)(stp);
    float4 st1 = *(const float4*)(stp + 4);
    const float inv3 = 1.0f / 3.0f;

    for (int rr = 0; rr < 4; ++rr) {
        const int row = row0 + rr;
        const size_t base = ((size_t)b * NN + row) * DD + lane * 8;
        float4 hg0 = *(const float4*)(h_gat + base);
        float4 hg1 = *(const float4*)(h_gat + base + 4);
        float4 n0 = *(const float4*)(noise_s + base);
        float4 n1 = *(const float4*)(noise_s + base + 4);
        float dot = hg0.x*st0.x + hg0.y*st0.y + hg0.z*st0.z + hg0.w*st0.w
                  + hg1.x*st1.x + hg1.y*st1.y + hg1.z*st1.z + hg1.w*st1.w;
        float nn = n0.x*n0.x + n0.y*n0.y + n0.z*n0.z + n0.w*n0.w
                 + n1.x*n1.x + n1.y*n1.y + n1.z*n1.z + n1.w*n1.w;
        #pragma unroll
        for (int off = 1; off < 64; off <<= 1) {
            dot += __shfl_xor(dot, off);
            nn  += __shfl_xor(nn, off);
        }
        const float sim = dot / 22.62741699796952f;   // / sqrt(512)
        const float al = 1.0f / (1.0f + expf(-sim));
        const float ns = 0.4f / fmaxf(sqrtf(nn), 1e-12f);

        float hm, sg, hn[8];
        float hgv[8] = {hg0.x,hg0.y,hg0.z,hg0.w,hg1.x,hg1.y,hg1.z,hg1.w};
        float stv[8] = {st0.x,st0.y,st0.z,st0.w,st1.x,st1.y,st1.z,st1.w};
        float nv [8] = {n0.x,n0.y,n0.z,n0.w,n1.x,n1.y,n1.z,n1.w};
        #pragma unroll
        for (int c = 0; c < 8; ++c) {
            hm = (1.0f - al) * hgv[c] + al * stv[c];
            sg = (hm > 0.f) ? 1.f : ((hm < 0.f) ? -1.f : 0.f);
            hn[c] = hm + sg * nv[c] * ns;
        }
        float4 w0 = make_float4(hn[0], hn[1], hn[2], hn[3]);
        float4 w1 = make_float4(hn[4], hn[5], hn[6], hn[7]);
        *(float4*)(h_out + base) = w0;
        *(float4*)(h_out + base + 4) = w1;
        if (first) {
            float4 ea = make_float4(hn[0]*inv3, hn[1]*inv3, hn[2]*inv3, hn[3]*inv3);
            float4 eb = make_float4(hn[4]*inv3, hn[5]*inv3, hn[6]*inv3, hn[7]*inv3);
            *(float4*)(embs + base) = ea;
            *(float4*)(embs + base + 4) = eb;
        } else {
            float4 ea = *(const float4*)(embs + base);
            float4 eb = *(const float4*)(embs + base + 4);
            ea.x += hn[0]*inv3; ea.y += hn[1]*inv3; ea.z += hn[2]*inv3; ea.w += hn[3]*inv3;
            eb.x += hn[4]*inv3; eb.y += hn[5]*inv3; eb.z += hn[6]*inv3; eb.w += hn[7]*inv3;
            *(float4*)(embs + base) = ea;
            *(float4*)(embs + base + 4) = eb;
        }
    }
}

// ---------------------------------------------------------------- K3: attention pooling star update
__global__ __launch_bounds__(256) void k_attpool(const float* __restrict__ h,
                                                 const float* __restrict__ star_in,
                                                 const float* __restrict__ mask,
                                                 float* __restrict__ star_out) {
    __shared__ float starS[DD];
    __shared__ float simS[NN];
    __shared__ float wS[NN];
    __shared__ float sh_M, sh_inv;
    const int b = blockIdx.x;
    const int tid = threadIdx.x;
    starS[tid] = star_in[b * DD + tid];
    starS[tid + 256] = star_in[b * DD + tid + 256];
    __syncthreads();
    const int wave = tid >> 6, lane = tid & 63;
    const float* hb = h + (size_t)b * NN * DD;
    float4 sv0 = *(const float4*)(&starS[lane * 8]);
    float4 sv1 = *(const float4*)(&starS[lane * 8 + 4]);
    for (int q = 0; q < 32; ++q) {
        const int n = wave * 32 + q;
        const float* hr = hb + n * DD + lane * 8;
        float4 h0 = *(const float4*)(hr);
        float4 h1 = *(const float4*)(hr + 4);
        float dot = h0.x*sv0.x + h0.y*sv0.y + h0.z*sv0.z + h0.w*sv0.w
                  + h1.x*sv1.x + h1.y*sv1.y + h1.z*sv1.z + h1.w*sv1.w;
        #pragma unroll
        for (int off = 1; off < 64; off <<= 1) dot += __shfl_xor(dot, off);
        if (lane == 0) simS[n] = dot;
    }
    __syncthreads();
    if (tid < 64) {
        float v = fmaxf(simS[tid], simS[tid + 64]);
        #pragma unroll
        for (int off = 1; off < 64; off <<= 1) v = fmaxf(v, __shfl_xor(v, off));
        if (tid == 0) sh_M = v;
    }
    __syncthreads();
    const float M = sh_M;
    if (tid < NN) wS[tid] = expf(simS[tid] - M) * mask[b * NN + tid];
    __syncthreads();
    if (tid < 64) {
        float v = wS[tid] + wS[tid + 64];
        #pragma unroll
        for (int off = 1; off < 64; off <<= 1) v += __shfl_xor(v, off);
        if (tid == 0) sh_inv = 1.0f / (v + 1e-24f * expf(-M));
    }
    __syncthreads();
    const float inv = sh_inv;
    float acc0 = 0.f, acc1 = 0.f;
    for (int n = 0; n < NN; ++n) {
        const float w = wS[n];
        acc0 += w * hb[n * DD + tid];
        acc1 += w * hb[n * DD + tid + 256];
    }
    star_out[b * DD + tid] = acc0 * inv;
    star_out[b * DD + tid + 256] = acc1 * inv;
}

// ----------------------------------------------------------------
extern "C" void kernel_launch(void* const* d_in, const int* in_sizes, int n_in,
                              void* d_out, int out_size, void* d_ws, size_t ws_size,
                              hipStream_t stream) {
    const int*   A      = (const int*)d_in[0];
    const float* hidden = (const float*)d_in[1];
    const float* mask   = (const float*)d_in[2];
    const float* a0     = (const float*)d_in[3];
    const float* a1     = (const float*)d_in[4];
    const float* a2     = (const float*)d_in[5];
    const float* a3     = (const float*)d_in[6];
    const float* noise  = (const float*)d_in[7];

    float* out_h    = (float*)d_out;
    float* out_star = out_h + (size_t)BB * NN * DD;
    float* out_embs = out_star + (size_t)BB * DD;

    float* ws_h    = (float*)d_ws;
    float* ws_star = ws_h + (size_t)BB * NN * DD;

    k_avepool<<<BB, 256, 0, stream>>>(hidden, mask, ws_star);

    for (int s = 0; s < 3; ++s) {
        const float* hin = (s == 0) ? hidden : ws_h;
        k_gat<<<BB, 1024, 0, stream>>>(hin, A, a0, a1, a2, a3, out_h);
        const float* ns = noise + (size_t)s * BB * NN * DD;
        float* hout = (s == 2) ? out_h : ws_h;
        k_mix<<<dim3(8, BB), 256, 0, stream>>>(out_h, ws_star, ns, hout, out_embs, (s == 0) ? 1 : 0);
        float* so = (s == 2) ? out_star : ws_star;
        k_attpool<<<BB, 256, 0, stream>>>(hout, ws_star, mask, so);
    }
}